// Round 3
// baseline (90.199 us; speedup 1.0000x reference)
//
#include <hip/hip_runtime.h>

// PolynomialRegression via bf16 MFMA, L2-direct (no LDS, no barriers):
//   y[b][o] = bias_o + sum_i x[b][i] * ( (U_o x[b])_i + W1[o][i] )
// T = X_bf16 @ G^T as 4096x2560x256 GEMM, 128x128 tiles, frags loaded
// straight from L2 (whole problem is L2-resident: X 2MB, G 1.3MB, x 4MB).
// Odd n-tiles (i>=128) skip k<128 (G identically zero there): -25% MFMA.

#define DD 256
#define NF 33153
#define TPB 256

typedef __attribute__((ext_vector_type(8))) short short8;
typedef __attribute__((ext_vector_type(4))) float floatx4;
typedef __attribute__((ext_vector_type(4))) unsigned short ushortx4;

__device__ inline unsigned short f2bf(float f) {
    unsigned u = __builtin_bit_cast(unsigned, f);
    return (unsigned short)((u + 0x7FFFu + ((u >> 16) & 1u)) >> 16);  // RNE
}

// --- fused prep: X fp32->bf16 | scatter W2 into dense G (2560x256) | out<-bias ---
__global__ __launch_bounds__(TPB)
void prep_kernel(const float* __restrict__ x, const float* __restrict__ W,
                 unsigned short* __restrict__ Xbf, unsigned short* __restrict__ G,
                 float* __restrict__ out) {
    int b = blockIdx.x;
    if (b < 1024) {                       // X conversion: 4 elems/thread
        int i = (b * TPB + threadIdx.x) * 4;
        float4 v = *(const float4*)&x[i];
        ushortx4 r;
        r.x = f2bf(v.x); r.y = f2bf(v.y); r.z = f2bf(v.z); r.w = f2bf(v.w);
        *(ushortx4*)&Xbf[i] = r;
    } else if (b < 1024 + 2560) {         // G row (o,i): U_o[i][j], 0 for j<i
        int oi = b - 1024;
        int o = oi >> 8, i = oi & 255;
        int j = threadIdx.x;
        int base = o * NF + 257 + i * DD - (i * (i - 1)) / 2 - i;  // + j for j>=i
        float v = (j >= i) ? W[base + j] : 0.f;
        G[oi * DD + j] = f2bf(v);
    } else {                              // out init with bias_o
        int e = (b - 3584) * TPB + threadIdx.x;   // 0..40959
        out[e] = W[(e % 10) * NF];
    }
}

// --- main: barrier-free GEMM tile + fused quadratic-form epilogue ---
__global__ __launch_bounds__(TPB)
void PolynomialRegression_75385265979710_kernel(const float* __restrict__ x,
                                                const float* __restrict__ W,
                                                const unsigned short* __restrict__ Xbf,
                                                const unsigned short* __restrict__ G,
                                                float* __restrict__ out) {
    const int tid  = threadIdx.x;
    const int lane = tid & 63;
    const int ln   = lane & 15;
    const int quad = lane >> 4;
    const int wave = tid >> 6;
    const int mw = wave & 1, nw = wave >> 1;
    const int mb = blockIdx.x, nb = blockIdx.y;
    const int o = nb >> 1, ihalf = nb & 1;
    const int m0 = mb * 128 + mw * 64;     // a rows: m0 + mt*16 + ln
    const int n0 = nb * 128 + nw * 64;     // b rows (G): n0 + nt*16 + ln
    const int i0 = ihalf * 128 + nw * 64;  // i index: i0 + nt*16 + ln

    const unsigned short* ap[4];
    const unsigned short* bp[4];
#pragma unroll
    for (int t = 0; t < 4; ++t) {
        ap[t] = Xbf + (m0 + t * 16 + ln) * DD + quad * 8;
        bp[t] = G   + (n0 + t * 16 + ln) * DD + quad * 8;
    }

    floatx4 acc[4][4];
#pragma unroll
    for (int mt = 0; mt < 4; ++mt)
#pragma unroll
        for (int nt = 0; nt < 4; ++nt) acc[mt][nt] = (floatx4)0.f;

#define KSTEP(kt) { \
        const int kk = (kt) * 32; \
        short8 a[4], b[4]; \
        _Pragma("unroll") for (int t = 0; t < 4; ++t) a[t] = *(const short8*)(ap[t] + kk); \
        _Pragma("unroll") for (int t = 0; t < 4; ++t) b[t] = *(const short8*)(bp[t] + kk); \
        _Pragma("unroll") for (int mt = 0; mt < 4; ++mt) \
        _Pragma("unroll") for (int nt = 0; nt < 4; ++nt) \
            acc[mt][nt] = __builtin_amdgcn_mfma_f32_16x16x32_bf16(a[mt], b[nt], acc[mt][nt], 0, 0, 0); \
    }

    if (ihalf == 0) {
#pragma unroll
        for (int kt = 0; kt < 8; ++kt) KSTEP(kt)
    } else {                               // G[n][k]==0 for k<128 here
#pragma unroll
        for (int kt = 4; kt < 8; ++kt) KSTEP(kt)
    }
#undef KSTEP

    // Epilogue: y_part[m] = sum_{i in tile} x_f32[m][i] * (T[m][i] + W1[o][i])
    float w1[4];
#pragma unroll
    for (int nt = 0; nt < 4; ++nt)
        w1[nt] = W[o * NF + 1 + i0 + nt * 16 + ln];

#pragma unroll
    for (int mt = 0; mt < 4; ++mt) {
#pragma unroll
        for (int r = 0; r < 4; ++r) {
            const int m = m0 + mt * 16 + quad * 4 + r;   // C/D: row=quad*4+reg, col=ln
            float p = 0.f;
#pragma unroll
            for (int nt = 0; nt < 4; ++nt) {
                float xv = x[m * DD + i0 + nt * 16 + ln];
                p = fmaf(xv, acc[mt][nt][r] + w1[nt], p);
            }
            p += __shfl_xor(p, 1);
            p += __shfl_xor(p, 2);
            p += __shfl_xor(p, 4);
            p += __shfl_xor(p, 8);
            if (ln == 0) atomicAdd(&out[m * 10 + o], p);  // 4-way contention
        }
    }
}

extern "C" void kernel_launch(void* const* d_in, const int* in_sizes, int n_in,
                              void* d_out, int out_size, void* d_ws, size_t ws_size,
                              hipStream_t stream) {
    const float* x = (const float*)d_in[0];   // (4096, 256)
    const float* W = (const float*)d_in[1];   // (10, 33153)
    float* out = (float*)d_out;               // (4096, 10)

    unsigned short* Xbf = (unsigned short*)d_ws;            // 2 MB
    unsigned short* G   = Xbf + 4096 * DD;                  // 1.31 MB

    prep_kernel<<<1024 + 2560 + 160, TPB, 0, stream>>>(x, W, Xbf, G, out);

    dim3 grid(4096 / 128, 20);   // (32, 20): nb -> (o = nb>>1, ihalf = nb&1)
    PolynomialRegression_75385265979710_kernel<<<grid, TPB, 0, stream>>>(x, W, Xbf, G, out);
}

// Round 4
// 73.578 us; speedup vs baseline: 1.2259x; 1.2259x over previous
//
#include <hip/hip_runtime.h>

// PolynomialRegression via bf16 MFMA:
//   y[b][o] = bias_o + sum_i x[b][i] * ( (U_o x[b])_i + W1[o][i] )
// G (2560x256 bf16) = stacked upper-triangular U_o rows (prebuilt, L2-hot).
// Main: per block (64 rows, one o): stage x-tile fp32->bf16 into LDS once
// (1 barrier), full-K MFMA loop with triangle skip (wave w skips kt<w),
// fused fp32 quadratic-form epilogue, direct stores. 2 launches total.

#define DD 256
#define NF 33153
#define BM 64
#define TPB 256
#define ASTRIDE 264   // 256 + 8 bf16 pad

typedef __attribute__((ext_vector_type(8))) short short8;
typedef __attribute__((ext_vector_type(4))) float floatx4;

__device__ inline unsigned short f2bf(float f) {
    unsigned u = __builtin_bit_cast(unsigned, f);
    return (unsigned short)((u + 0x7FFFu + ((u >> 16) & 1u)) >> 16);  // RNE
}

// --- prep: scatter W2 into dense upper-triangular G (2560x256 bf16) ---
__global__ __launch_bounds__(TPB)
void gbuild_kernel(const float* __restrict__ W, unsigned short* __restrict__ G) {
    int oi = blockIdx.x;            // o*256 + i
    int o = oi >> 8, i = oi & 255;
    int j = threadIdx.x;
    int base = o * NF + 257 + i * DD - (i * (i - 1)) / 2 - i;   // + j for j>=i
    float v = (j >= i) ? W[base + j] : 0.f;
    G[oi * DD + j] = f2bf(v);
}

// --- main: stage-once GEMM + fused quadratic-form epilogue ---
__global__ __launch_bounds__(TPB, 3)
void PolynomialRegression_75385265979710_kernel(const float* __restrict__ x,
                                                const float* __restrict__ W,
                                                const unsigned short* __restrict__ G,
                                                float* __restrict__ out) {
    __shared__ __align__(16) unsigned short As[BM * ASTRIDE];  // 33792 B
    __shared__ float red[4 * BM];                              // 1 KB

    const int tid  = threadIdx.x;
    const int lane = tid & 63;
    const int wave = tid >> 6;
    const int ln   = lane & 15;
    const int quad = lane >> 4;
    const int rowbase = blockIdx.x * BM;
    const int o   = blockIdx.y;
    const int wn0 = wave * 64;     // this wave's i-range: [wn0, wn0+64)

    // Stage + convert: 64 rows x 256 k fp32 -> bf16 LDS. 8 floats/thread/iter.
#pragma unroll
    for (int it = 0; it < 8; ++it) {
        int idx = it * 2048 + tid * 8;
        int r = idx >> 8, c = idx & 255;
        float4 v0 = *(const float4*)&x[(rowbase + r) * DD + c];
        float4 v1 = *(const float4*)&x[(rowbase + r) * DD + c + 4];
        short8 p;
        p[0] = (short)f2bf(v0.x); p[1] = (short)f2bf(v0.y);
        p[2] = (short)f2bf(v0.z); p[3] = (short)f2bf(v0.w);
        p[4] = (short)f2bf(v1.x); p[5] = (short)f2bf(v1.y);
        p[6] = (short)f2bf(v1.z); p[7] = (short)f2bf(v1.w);
        *(short8*)&As[r * ASTRIDE + c] = p;
    }
    __syncthreads();

    floatx4 acc[4][4];
#pragma unroll
    for (int mt = 0; mt < 4; ++mt)
#pragma unroll
        for (int nt = 0; nt < 4; ++nt) acc[mt][nt] = (floatx4)0.f;

    const unsigned short* bp[4];
#pragma unroll
    for (int t = 0; t < 4; ++t)
        bp[t] = G + (o * DD + wn0 + t * 16 + ln) * DD + quad * 8;

    // MFMA loop, no barriers. G[o,i][k]==0 for k<i => wave w skips kt<w.
#pragma unroll
    for (int kt = 0; kt < 4; ++kt) {
        if (kt >= wave) {
#pragma unroll
            for (int ks = 0; ks < 2; ++ks) {
                const int kk = kt * 64 + ks * 32;
                short8 a[4], b[4];
#pragma unroll
                for (int nt = 0; nt < 4; ++nt)
                    b[nt] = *(const short8*)(bp[nt] + kk);    // L2-hot G
#pragma unroll
                for (int mt = 0; mt < 4; ++mt)
                    a[mt] = *(const short8*)&As[(mt * 16 + ln) * ASTRIDE + kk + quad * 8];
#pragma unroll
                for (int mt = 0; mt < 4; ++mt)
#pragma unroll
                    for (int nt = 0; nt < 4; ++nt)
                        acc[mt][nt] = __builtin_amdgcn_mfma_f32_16x16x32_bf16(
                            a[mt], b[nt], acc[mt][nt], 0, 0, 0);
            }
        }
    }

    // Epilogue: y_part[m] = sum_{i in wave's range} x_f32[m][i]*(T[m][i]+W1[o][i])
    float w1[4];
#pragma unroll
    for (int nt = 0; nt < 4; ++nt)
        w1[nt] = W[o * NF + 1 + wn0 + nt * 16 + ln];

#pragma unroll
    for (int mt = 0; mt < 4; ++mt) {
#pragma unroll
        for (int r = 0; r < 4; ++r) {
            const int m = mt * 16 + quad * 4 + r;   // C/D: row=quad*4+reg, col=ln
            float p = 0.f;
#pragma unroll
            for (int nt = 0; nt < 4; ++nt) {
                float xv = x[(rowbase + m) * DD + wn0 + nt * 16 + ln];
                p = fmaf(xv, acc[mt][nt][r] + w1[nt], p);
            }
            p += __shfl_xor(p, 1);
            p += __shfl_xor(p, 2);
            p += __shfl_xor(p, 4);
            p += __shfl_xor(p, 8);
            if (ln == 0) red[wave * BM + m] = p;
        }
    }
    __syncthreads();

    if (tid < BM) {
        const int m = tid;
        float s = red[m] + red[BM + m] + red[2 * BM + m] + red[3 * BM + m] + W[o * NF];
        out[(rowbase + m) * 10 + o] = s;
    }
}

extern "C" void kernel_launch(void* const* d_in, const int* in_sizes, int n_in,
                              void* d_out, int out_size, void* d_ws, size_t ws_size,
                              hipStream_t stream) {
    const float* x = (const float*)d_in[0];   // (4096, 256)
    const float* W = (const float*)d_in[1];   // (10, 33153)
    float* out = (float*)d_out;               // (4096, 10)

    unsigned short* G = (unsigned short*)d_ws;   // 1.31 MB

    gbuild_kernel<<<10 * DD, TPB, 0, stream>>>(W, G);

    dim3 grid(4096 / BM, 10);
    PolynomialRegression_75385265979710_kernel<<<grid, TPB, 0, stream>>>(x, W, G, out);
}

// Round 5
// 71.646 us; speedup vs baseline: 1.2590x; 1.0270x over previous
//
#include <hip/hip_runtime.h>

// PolynomialRegression, single fused kernel (no workspace, no prep launches):
//   y[b][o] = bias_o + sum_i x[b][i] * ( (U_o x[b])_i + W1[o][i] )
// U_o rows are read DIRECTLY from W (fp32, L2-hot) as MFMA B-frags with
// in-register half-up bf16 pack; j<i masking only on the 4 diagonal frags.
// Triangle balanced: wave w owns i-groups {32w,+32} u {224-32w,+32}
// (pairs (0,7)(1,6)(2,5)(3,4)) -> every wave does exactly 72 MFMA.

#define DD 256
#define NF 33153
#define TPB 256
#define ASTRIDE 264   // bf16 elems; row stride 528 B -> 4-bank shift, 2-way (free)

typedef __attribute__((ext_vector_type(8))) short short8;
typedef __attribute__((ext_vector_type(4))) float floatx4;
typedef __attribute__((ext_vector_type(4), aligned(4))) float float4a;  // 4B-aligned

union S8U { unsigned u[4]; short8 s; };

__device__ inline unsigned pack2(float lo, float hi) {   // 2xfp32 -> bf16x2, half-up
    unsigned a = __builtin_bit_cast(unsigned, hi) + 0x8000u;
    unsigned b = __builtin_bit_cast(unsigned, lo) + 0x8000u;
    return __builtin_amdgcn_perm(a, b, 0x07060302u);     // [a.hi16 | b.hi16]
}

__global__ __launch_bounds__(TPB)
void PolynomialRegression_75385265979710_kernel(const float* __restrict__ x,
                                                const float* __restrict__ W,
                                                float* __restrict__ out) {
    __shared__ __align__(16) unsigned short As[64 * ASTRIDE];  // 33792 B
    __shared__ float red[4 * 64];

    const int tid  = threadIdx.x;
    const int lane = tid & 63, wave = tid >> 6;
    const int ln   = lane & 15, quad = lane >> 4;
    const int q8   = quad * 8;
    const int rowbase = blockIdx.x * 64;
    const int o  = blockIdx.y;
    const int g1 = wave, g2 = 7 - wave;

    // --- stage x-tile (64 rows x 256) fp32 -> bf16 into LDS ---
#pragma unroll
    for (int it = 0; it < 8; ++it) {
        int idx = it * 2048 + tid * 8;
        int r = idx >> 8, c = idx & 255;
        const float* src = &x[(rowbase + r) * DD + c];
        float4a v0 = *(const float4a*)src;
        float4a v1 = *(const float4a*)(src + 4);
        S8U p;
        p.u[0] = pack2(v0.x, v0.y); p.u[1] = pack2(v0.z, v0.w);
        p.u[2] = pack2(v1.x, v1.y); p.u[3] = pack2(v1.z, v1.w);
        *(short8*)&As[r * ASTRIDE + c] = p.s;
    }
    __syncthreads();

    // tiles: nt 0,1 -> i in [32*g1, +32); nt 2,3 -> i in [32*g2, +32)
    int iRow[4], bBase[4];
#pragma unroll
    for (int nt = 0; nt < 4; ++nt) {
        int g = (nt < 2) ? g1 : g2;
        int i = g * 32 + (nt & 1) * 16 + ln;
        iRow[nt]  = i;
        bBase[nt] = o * NF + 257 + i * 255 - ((i * (i - 1)) >> 1);  // + j, j>=i valid
    }

    floatx4 acc[4][4];
#pragma unroll
    for (int mt = 0; mt < 4; ++mt)
#pragma unroll
        for (int nt = 0; nt < 4; ++nt) acc[mt][nt] = (floatx4)0.f;

    auto loadA = [&](int kk, short8* a) {
#pragma unroll
        for (int mt = 0; mt < 4; ++mt)
            a[mt] = *(const short8*)&As[(mt * 16 + ln) * ASTRIDE + kk + q8];
    };
    auto loadB = [&](int nt, int kk) -> short8 {
        const float* p = &W[bBase[nt] + kk + q8];
        float4a w0 = *(const float4a*)p;
        float4a w1 = *(const float4a*)(p + 4);
        S8U r;
        r.u[0] = pack2(w0.x, w0.y); r.u[1] = pack2(w0.z, w0.w);
        r.u[2] = pack2(w1.x, w1.y); r.u[3] = pack2(w1.z, w1.w);
        return r.s;
    };
    auto loadBmask = [&](int nt, int kk) -> short8 {   // zero j<i (diagonal chunk)
        int di = iRow[nt] - kk;
        const float* p = &W[bBase[nt] + kk + q8];
        float4a w0 = *(const float4a*)p;
        float4a w1 = *(const float4a*)(p + 4);
        float f[8] = {w0.x, w0.y, w0.z, w0.w, w1.x, w1.y, w1.z, w1.w};
#pragma unroll
        for (int e = 0; e < 8; ++e)
            if (q8 + e < di) f[e] = 0.f;
        S8U r;
        r.u[0] = pack2(f[0], f[1]); r.u[1] = pack2(f[2], f[3]);
        r.u[2] = pack2(f[4], f[5]); r.u[3] = pack2(f[6], f[7]);
        return r.s;
    };
    auto mfma2 = [&](short8* a, short8 b0, short8 b1, int nlo) {
#pragma unroll
        for (int mt = 0; mt < 4; ++mt) {
            acc[mt][nlo]     = __builtin_amdgcn_mfma_f32_16x16x32_bf16(a[mt], b0, acc[mt][nlo],     0, 0, 0);
            acc[mt][nlo + 1] = __builtin_amdgcn_mfma_f32_16x16x32_bf16(a[mt], b1, acc[mt][nlo + 1], 0, 0, 0);
        }
    };

    {   // diagonal chunks (masked), one per group
        short8 a[4];
        loadA(g1 * 32, a);
        mfma2(a, loadBmask(0, g1 * 32), loadBmask(1, g1 * 32), 0);
        loadA(g2 * 32, a);
        mfma2(a, loadBmask(2, g2 * 32), loadBmask(3, g2 * 32), 2);
    }
    for (int c = g1 + 1; c <= g2; ++c) {   // group-1 only
        short8 a[4];
        loadA(c * 32, a);
        mfma2(a, loadB(0, c * 32), loadB(1, c * 32), 0);
    }
    for (int c = g2 + 1; c < 8; ++c) {     // both groups, shared A-frags
        short8 a[4];
        loadA(c * 32, a);
        mfma2(a, loadB(0, c * 32), loadB(1, c * 32), 0);
        mfma2(a, loadB(2, c * 32), loadB(3, c * 32), 2);
    }

    // --- epilogue: y_part[m] = sum_{i in wave's set} x_f32[m][i]*(T[m][i]+W1[o][i])
    float w1v[4];
#pragma unroll
    for (int nt = 0; nt < 4; ++nt)
        w1v[nt] = W[o * NF + 1 + iRow[nt]];

#pragma unroll
    for (int mt = 0; mt < 4; ++mt) {
#pragma unroll
        for (int r = 0; r < 4; ++r) {
            const int m = mt * 16 + quad * 4 + r;   // C/D: row=quad*4+reg, col=ln
            float p = 0.f;
#pragma unroll
            for (int nt = 0; nt < 4; ++nt) {
                float xv = x[(rowbase + m) * DD + iRow[nt]];
                p = fmaf(xv, acc[mt][nt][r] + w1v[nt], p);
            }
            p += __shfl_xor(p, 1);
            p += __shfl_xor(p, 2);
            p += __shfl_xor(p, 4);
            p += __shfl_xor(p, 8);
            if (ln == 0) red[wave * 64 + m] = p;
        }
    }
    __syncthreads();

    if (tid < 64) {
        float s = red[tid] + red[64 + tid] + red[128 + tid] + red[192 + tid] + W[o * NF];
        out[(rowbase + tid) * 10 + o] = s;
    }
}

extern "C" void kernel_launch(void* const* d_in, const int* in_sizes, int n_in,
                              void* d_out, int out_size, void* d_ws, size_t ws_size,
                              hipStream_t stream) {
    const float* x = (const float*)d_in[0];   // (4096, 256)
    const float* W = (const float*)d_in[1];   // (10, 33153)
    float* out = (float*)d_out;               // (4096, 10)

    dim3 grid(4096 / 64, 10);
    PolynomialRegression_75385265979710_kernel<<<grid, TPB, 0, stream>>>(x, W, out);
}